// Round 13
// baseline (87.346 us; speedup 1.0000x reference)
//
#include <hip/hip_runtime.h>
#include <math.h>

#define NROWS 262144
#define DIM   256
#define NC    64
#define CD    (NC*DIM)       // 16384
#define NBLK  512            // k_main blocks, 512 rows each

// ws float-offset layout:
//  cent_new [16384]      @ 0
//  s_final  [64]         @ 16384
//  abs_part [64]         @ 16448
//  pair_part[64]         @ 16512
//  s_part   [512*64]     @ 16576
//  s_stage2 [16*64]      @ 49344
//  stage2   [4*16384]    @ 50368
//  partials [512*16384]  @ 115904
#define OFF_CENT   0
#define OFF_SF     16384
#define OFF_ABS    16448
#define OFF_PAIR   16512
#define OFF_SPART  16576
#define OFF_SST2   49344
#define OFF_ST2    50368
#define OFF_PART   115904

typedef short  bf16x8 __attribute__((ext_vector_type(8)));
typedef float  f32x16 __attribute__((ext_vector_type(16)));

// DPP 64-lane sum: after these 6 adds, lane 63 holds the full sum.
#define DPP_ADD(v, ctrl) \
    ((v) + __int_as_float(__builtin_amdgcn_update_dpp(0, __float_as_int(v), (ctrl), 0xf, 0xf, true)))

__device__ __forceinline__ float dpp_sum64(float v) {
    v = DPP_ADD(v, 0x111);
    v = DPP_ADD(v, 0x112);
    v = DPP_ADD(v, 0x114);
    v = DPP_ADD(v, 0x118);
    v = DPP_ADD(v, 0x142);
    v = DPP_ADD(v, 0x143);
    return v;                // lane 63 = total
}

// pack two f32 -> two bf16 (RNE) in one u32 (lo = first)
__device__ __forceinline__ unsigned int bf16rne2(float lo, float hi) {
    unsigned int ul = __float_as_uint(lo);
    ul = (ul + 0x7FFFu + ((ul >> 16) & 1u)) >> 16;
    unsigned int uh = __float_as_uint(hi);
    uh = (uh + 0x7FFFu + ((uh >> 16) & 1u)) & 0xFFFF0000u;
    return ul | uh;
}

// MFMA for one 64-row chunk (4 ksteps x 2 class-tiles).
// pb: pair-packed u32 LDS [pr][col]: u32 = bf16(row 2pr)|bf16(row 2pr+1)<<16.
// B.u[p] holds k=j=2p (lo), j=2p+1 (hi): same pairing as the proven layout.
__device__ __forceinline__ void do_mfma_chunk(const unsigned int* pb,
                                              const int* tgts, int rbase,
                                              int lane, int d0,
                                              f32x16& a0r, f32x16& a1r)
{
    const int g8  = (lane >> 5) << 3;
    const int prb = (lane >> 5) << 2;          // g8/2
    const int cA  = lane & 31;
    const int cB  = 32 + cA;
    const int col = d0 + cA;
    #pragma unroll
    for (int ks = 0; ks < 4; ++ks) {
        const int rA = rbase + ks * 16 + g8;
        const int t0 = tgts[rA+0], t1 = tgts[rA+1], t2 = tgts[rA+2], t3 = tgts[rA+3];
        const int t4 = tgts[rA+4], t5 = tgts[rA+5], t6 = tgts[rA+6], t7 = tgts[rA+7];
        union { unsigned int u[4]; bf16x8 v; } A0, A1, B;
        A0.u[0] = ((t0==cA)?0x3F80u:0u) | (((t1==cA)?0x3F80u:0u) << 16);
        A0.u[1] = ((t2==cA)?0x3F80u:0u) | (((t3==cA)?0x3F80u:0u) << 16);
        A0.u[2] = ((t4==cA)?0x3F80u:0u) | (((t5==cA)?0x3F80u:0u) << 16);
        A0.u[3] = ((t6==cA)?0x3F80u:0u) | (((t7==cA)?0x3F80u:0u) << 16);
        A1.u[0] = ((t0==cB)?0x3F80u:0u) | (((t1==cB)?0x3F80u:0u) << 16);
        A1.u[1] = ((t2==cB)?0x3F80u:0u) | (((t3==cB)?0x3F80u:0u) << 16);
        A1.u[2] = ((t4==cB)?0x3F80u:0u) | (((t5==cB)?0x3F80u:0u) << 16);
        A1.u[3] = ((t6==cB)?0x3F80u:0u) | (((t7==cB)?0x3F80u:0u) << 16);
        const int pr0 = ks * 8 + prb;
        B.u[0] = pb[(pr0 + 0) * 256 + col];
        B.u[1] = pb[(pr0 + 1) * 256 + col];
        B.u[2] = pb[(pr0 + 2) * 256 + col];
        B.u[3] = pb[(pr0 + 3) * 256 + col];
        a0r = __builtin_amdgcn_mfma_f32_32x32x16_bf16(A0.v, B.v, a0r, 0, 0, 0);
        a1r = __builtin_amdgcn_mfma_f32_32x32x16_bf16(A1.v, B.v, a1r, 0, 0, 0);
    }
}

// ---- k_main: streaming MFMA scatter-add; dbuf + load-over-MFMA pipeline ----
__global__ __launch_bounds__(512, 4)
void k_main(const float* __restrict__ pred, const float* __restrict__ cent,
            const float* __restrict__ count, const int* __restrict__ tgt,
            float* __restrict__ ws)
{
    __shared__ unsigned int pbuf[2][32 * 256];   // 2 x 32 KB pair-packed bf16
    __shared__ int   tgt_s[512];
    __shared__ float inv_s[64];
    __shared__ float vec_s[512];
    __shared__ float sw_s[8][64];

    const int tid  = threadIdx.x;
    const int w    = tid >> 6;        // 8 waves; wave owns dims [32w, 32w+32)
    const int lane = tid & 63;
    const int base = blockIdx.x * 512;

    tgt_s[tid] = tgt[base + tid];
    if (tid < 64) inv_s[tid] = 1.0f / count[tid];
    __syncthreads();

    const float4* pred4 = (const float4*)pred;
    const float4* cent4 = (const float4*)cent;
    const int d0 = w * 32;

    f32x16 acc0 = {};   // classes [0,32)  x dims [d0,d0+32)
    f32x16 acc1 = {};   // classes [32,64) x dims [d0,d0+32)

// wave w owns row pairs (16i+2w, 16i+2w+1), i=0..3 -> pair-rows pr = 8i+w
#define PREDLOAD(rbq)                                                          \
        const int rb = (rbq);                                                  \
        const size_t gp = (size_t)(base + rb) * 64 + lane;                     \
        float4 pE0 = pred4[gp + (size_t)(2*w +  0) * 64];                      \
        float4 pO0 = pred4[gp + (size_t)(2*w +  1) * 64];                      \
        float4 pE1 = pred4[gp + (size_t)(2*w + 16) * 64];                      \
        float4 pO1 = pred4[gp + (size_t)(2*w + 17) * 64];                      \
        float4 pE2 = pred4[gp + (size_t)(2*w + 32) * 64];                      \
        float4 pO2 = pred4[gp + (size_t)(2*w + 33) * 64];                      \
        float4 pE3 = pred4[gp + (size_t)(2*w + 48) * 64];                      \
        float4 pO3 = pred4[gp + (size_t)(2*w + 49) * 64];

#define PP(i, pE, pO, ceE, ceO, cE, cO)                                        \
    {                                                                          \
        const float ivE = inv_s[cE], ivO = inv_s[cO];                          \
        float dx = ceE.x - pE.x * ivE, dy = ceE.y - pE.y * ivE;                \
        float dz = ceE.z - pE.z * ivE, dw = ceE.w - pE.w * ivE;                \
        float ssE = dx*dx + dy*dy + dz*dz + dw*dw;                             \
        dx = ceO.x - pO.x * ivO; dy = ceO.y - pO.y * ivO;                      \
        dz = ceO.z - pO.z * ivO; dw = ceO.w - pO.w * ivO;                      \
        float ssO = dx*dx + dy*dy + dz*dz + dw*dw;                             \
        ssE = dpp_sum64(ssE); ssO = dpp_sum64(ssO);                            \
        if (lane == 63) { vec_s[rb + 16*(i) + 2*w    ] = sqrtf(ssE);           \
                          vec_s[rb + 16*(i) + 2*w + 1] = sqrtf(ssO); }         \
        uint4 u;                                                               \
        u.x = bf16rne2(pE.x, pO.x); u.y = bf16rne2(pE.y, pO.y);                \
        u.z = bf16rne2(pE.z, pO.z); u.w = bf16rne2(pE.w, pO.w);                \
        *(uint4*)&pbuf[bnext][(8*(i) + w) * 256 + 4 * lane] = u;               \
    }

#define STAGEREST(bn)                                                          \
        const int bnext = (bn);                                                \
        const int cE0 = tgt_s[rb + 2*w +  0], cO0 = tgt_s[rb + 2*w +  1];      \
        const int cE1 = tgt_s[rb + 2*w + 16], cO1 = tgt_s[rb + 2*w + 17];      \
        const int cE2 = tgt_s[rb + 2*w + 32], cO2 = tgt_s[rb + 2*w + 33];      \
        const int cE3 = tgt_s[rb + 2*w + 48], cO3 = tgt_s[rb + 2*w + 49];      \
        const float4 ceE0 = cent4[(size_t)cE0 * 64 + lane];                    \
        const float4 ceO0 = cent4[(size_t)cO0 * 64 + lane];                    \
        const float4 ceE1 = cent4[(size_t)cE1 * 64 + lane];                    \
        const float4 ceO1 = cent4[(size_t)cO1 * 64 + lane];                    \
        const float4 ceE2 = cent4[(size_t)cE2 * 64 + lane];                    \
        const float4 ceO2 = cent4[(size_t)cO2 * 64 + lane];                    \
        const float4 ceE3 = cent4[(size_t)cE3 * 64 + lane];                    \
        const float4 ceO3 = cent4[(size_t)cO3 * 64 + lane];                    \
        PP(0, pE0, pO0, ceE0, ceO0, cE0, cO0)                                  \
        PP(1, pE1, pO1, ceE1, ceO1, cE1, cO1)                                  \
        PP(2, pE2, pO2, ceE2, ceO2, cE2, cO2)                                  \
        PP(3, pE3, pO3, ceE3, ceO3, cE3, cO3)

    // prologue: stage chunk 0 into buf 0
    {
        PREDLOAD(0)
        STAGEREST(0)
    }
    __syncthreads();

    int cur = 0;
    #pragma unroll 1
    for (int ch = 0; ch < 7; ++ch) {
        PREDLOAD((ch + 1) * 64)                              // in flight under MFMA
        do_mfma_chunk(pbuf[cur], tgt_s, ch * 64, lane, d0, acc0, acc1);
        STAGEREST(cur ^ 1)                                   // consume + pack + write
        __syncthreads();                                     // ONE barrier per chunk
        cur ^= 1;
    }
    do_mfma_chunk(pbuf[cur], tgt_s, 7 * 64, lane, d0, acc0, acc1);

#undef PREDLOAD
#undef PP
#undef STAGEREST

    // write f32 partials (C/D layout: col=lane&31, row=(reg&3)+8*(reg>>2)+4*(lane>>5))
    float* pp = ws + OFF_PART + (size_t)blockIdx.x * CD;
    const int dim = d0 + (lane & 31);
    #pragma unroll
    for (int reg = 0; reg < 16; ++reg) {
        const int crow = (reg & 3) + 8 * (reg >> 2) + 4 * (lane >> 5);
        pp[(     crow) * 256 + dim] = acc0[reg];
        pp[(32 + crow) * 256 + dim] = acc1[reg];
    }

    // block-end per-class s reduction (no atomics)
    {
        const float vv = vec_s[w * 64 + lane];
        const int   cc = tgt_s[w * 64 + lane];
        float accs = 0.f;
        for (int k = 0; k < NC; ++k) {
            float sel = (cc == k) ? vv : 0.f;
            sel = dpp_sum64(sel);
            const float tot = __shfl(sel, 63, 64);
            accs += (lane == k) ? tot : 0.f;
        }
        sw_s[w][lane] = accs;
    }
    __syncthreads();
    if (w == 0) {
        float s = 0.f;
        #pragma unroll
        for (int q = 0; q < 8; ++q) s += sw_s[q][lane];
        ws[OFF_SPART + blockIdx.x * 64 + lane] = s;
    }
}

// ---- k_red (WIDE): 1024 blocks reduce partials -> 4 stage2 slabs;
//      16 blocks reduce s_part -> 16 s_stage2 rows ----
__global__ __launch_bounds__(256)
void k_red(float* __restrict__ ws)
{
    const int b = blockIdx.x, t = threadIdx.x;
    __shared__ float red[4][64];
    if (b < 1024) {
        const int pg = b >> 8, eg = b & 255;
        const int e  = eg * 64 + (t & 63);
        const int ps = t >> 6;                     // 0..3
        const float* pp = ws + OFF_PART + e;
        float s = 0.f;
        const int pstart = pg * 128 + ps * 32;
        #pragma unroll 8
        for (int p = pstart; p < pstart + 32; ++p) s += pp[(size_t)p * CD];
        red[ps][t & 63] = s;
        __syncthreads();
        if (t < 64)
            ws[OFF_ST2 + pg * CD + eg * 64 + t]
                = red[0][t] + red[1][t] + red[2][t] + red[3][t];
    } else {
        const int q = b - 1024;                    // 0..15
        const int c = t & 63, pq = t >> 6;
        float s = 0.f;
        #pragma unroll
        for (int i = 0; i < 8; ++i)
            s += ws[OFF_SPART + (q * 32 + pq * 8 + i) * 64 + c];
        red[pq][c] = s;
        __syncthreads();
        if (t < 64)
            ws[OFF_SST2 + q * 64 + t]
                = red[0][t] + red[1][t] + red[2][t] + red[3][t];
    }
}

// ---- k2: cent_new = cent + acc*inv; abs partials; s_final ----
__global__ __launch_bounds__(256)
void k2_build(const float* __restrict__ cent, const float* __restrict__ count,
              const float* __restrict__ dist, float* __restrict__ ws)
{
    const int c = blockIdx.x, i = threadIdx.x;
    const float inv = 1.0f / count[c];
    const int o = c * 256 + i;
    float tsum = 0.f;
    #pragma unroll
    for (int pg = 0; pg < 4; ++pg) tsum += ws[OFF_ST2 + pg * CD + o];
    const float val = cent[o] + tsum * inv;
    ws[OFF_CENT + o] = val;
    float a = fabsf(val);
    #pragma unroll
    for (int off = 32; off > 0; off >>= 1) a += __shfl_xor(a, off, 64);
    __shared__ float ra[4];
    if ((i & 63) == 0) ra[i >> 6] = a;
    __syncthreads();
    if (i == 0) {
        float sv = 0.f;
        #pragma unroll
        for (int q = 0; q < 16; ++q) sv += ws[OFF_SST2 + q * 64 + c];
        ws[OFF_ABS + c] = ra[0] + ra[1] + ra[2] + ra[3];
        ws[OFF_SF  + c] = sqrtf(dist[c] + sv) / count[c];
    }
}

// ---- k3: pairwise terms ----
__global__ __launch_bounds__(256)
void k3_pairs(const float* __restrict__ cw, float* __restrict__ ws)
{
    const int i    = blockIdx.x;
    const int tid  = threadIdx.x;
    const int lane = tid & 63;
    const int w    = tid >> 6;
    const float4* c4 = (const float4*)(ws + OFF_CENT);
    const float*  sf = ws + OFF_SF;

    float4 ci = c4[i * 64 + lane];
    float  si = sf[i];
    float acc = 0.f;
    for (int j = w; j < NC; j += 4) {
        if (j == i) continue;
        float4 cj = c4[j * 64 + lane];
        float dx = ci.x - cj.x, dy = ci.y - cj.y;
        float dz = ci.z - cj.z, dw = ci.w - cj.w;
        float ss = dx*dx + dy*dy + dz*dz + dw*dw;
        #pragma unroll
        for (int o = 32; o > 0; o >>= 1) ss += __shfl_xor(ss, o, 64);
        acc += cw[i * NC + j] * (si + sf[j]) / sqrtf(ss);
    }
    __shared__ float wsum[4];
    if (lane == 0) wsum[w] = acc;
    __syncthreads();
    if (tid == 0) ws[OFF_PAIR + i] = wsum[0] + wsum[1] + wsum[2] + wsum[3];
}

// ---- k4: final scalar ----
__global__ __launch_bounds__(64)
void k4_final(const float* __restrict__ ws, float* __restrict__ out)
{
    const int t = threadIdx.x;
    float a = ws[OFF_ABS + t];
    float p = ws[OFF_PAIR + t];
    #pragma unroll
    for (int o = 32; o > 0; o >>= 1) {
        a += __shfl_xor(a, o, 64);
        p += __shfl_xor(p, o, 64);
    }
    if (t == 0) out[0] = p / 64.0f * 63.0f + a * 1e-6f;
}

extern "C" void kernel_launch(void* const* d_in, const int* in_sizes, int n_in,
                              void* d_out, int out_size, void* d_ws, size_t ws_size,
                              hipStream_t stream)
{
    const float* pred  = (const float*)d_in[0];
    const float* cent  = (const float*)d_in[1];
    const float* dist  = (const float*)d_in[2];
    const float* count = (const float*)d_in[3];
    const float* cw    = (const float*)d_in[4];
    const int*   tgt   = (const int*)d_in[5];
    float* ws  = (float*)d_ws;
    float* out = (float*)d_out;

    // no atomics anywhere -> no memset needed
    k_main  <<<NBLK, 512, 0, stream>>>(pred, cent, count, tgt, ws);
    k_red   <<<1040, 256, 0, stream>>>(ws);
    k2_build<<<NC,   256, 0, stream>>>(cent, count, dist, ws);
    k3_pairs<<<NC,   256, 0, stream>>>(cw, ws);
    k4_final<<<1,     64, 0, stream>>>(ws, out);
}

// Round 14
// 78.353 us; speedup vs baseline: 1.1148x; 1.1148x over previous
//
#include <hip/hip_runtime.h>
#include <math.h>

#define NROWS 262144
#define DIM   256
#define NC    64
#define CD    (NC*DIM)       // 16384
#define NBLK  512            // k_main blocks, 512 rows each

// ws float-offset layout:
//  cent_new [16384]      @ 0
//  s_final  [64]         @ 16384
//  abs_part [64]         @ 16448
//  pair_part[64]         @ 16512
//  s_part   [512*64]     @ 16576
//  s_stage2 [16*64]      @ 49344
//  stage2   [4*16384]    @ 50368
//  partials [512*16384]  @ 115904  (ushort/bf16 now: uses half the region)
#define OFF_CENT   0
#define OFF_SF     16384
#define OFF_ABS    16448
#define OFF_PAIR   16512
#define OFF_SPART  16576
#define OFF_SST2   49344
#define OFF_ST2    50368
#define OFF_PART   115904

typedef short  bf16x8 __attribute__((ext_vector_type(8)));
typedef float  f32x16 __attribute__((ext_vector_type(16)));

// DPP 64-lane sum: after these 6 adds, lane 63 holds the full sum.
#define DPP_ADD(v, ctrl) \
    ((v) + __int_as_float(__builtin_amdgcn_update_dpp(0, __float_as_int(v), (ctrl), 0xf, 0xf, true)))

__device__ __forceinline__ float dpp_sum64(float v) {
    v = DPP_ADD(v, 0x111);
    v = DPP_ADD(v, 0x112);
    v = DPP_ADD(v, 0x114);
    v = DPP_ADD(v, 0x118);
    v = DPP_ADD(v, 0x142);
    v = DPP_ADD(v, 0x143);
    return v;                // lane 63 = total
}

// pack two f32 -> two bf16 (RNE) in one u32 (lo = first)
__device__ __forceinline__ unsigned int bf16rne2(float lo, float hi) {
    unsigned int ul = __float_as_uint(lo);
    ul = (ul + 0x7FFFu + ((ul >> 16) & 1u)) >> 16;
    unsigned int uh = __float_as_uint(hi);
    uh = (uh + 0x7FFFu + ((uh >> 16) & 1u)) & 0xFFFF0000u;
    return ul | uh;
}
// single f32 -> bf16 ushort (RNE)
__device__ __forceinline__ unsigned short bf16rne1(float v) {
    unsigned int x = __float_as_uint(v);
    return (unsigned short)((x + 0x7FFFu + ((x >> 16) & 1u)) >> 16);
}
__device__ __forceinline__ float bflo(unsigned int u) { return __uint_as_float(u << 16); }
__device__ __forceinline__ float bfhi(unsigned int u) { return __uint_as_float(u & 0xFFFF0000u); }
__device__ __forceinline__ float bfup(unsigned short u) { return __uint_as_float(((unsigned int)u) << 16); }

// MFMA for one 64-row chunk (4 ksteps x 2 class-tiles); A-frags self-built.
__device__ __forceinline__ void do_mfma_chunk(const unsigned short* pb,
                                              const int* tgts, int rbase,
                                              int lane, int d0,
                                              f32x16& a0r, f32x16& a1r)
{
    const int g8  = (lane >> 5) << 3;
    const int cA  = lane & 31;
    const int cB  = 32 + cA;
    const int col = d0 + cA;
    #pragma unroll
    for (int ks = 0; ks < 4; ++ks) {
        const int rA = rbase + ks * 16 + g8;
        const int t0 = tgts[rA+0], t1 = tgts[rA+1], t2 = tgts[rA+2], t3 = tgts[rA+3];
        const int t4 = tgts[rA+4], t5 = tgts[rA+5], t6 = tgts[rA+6], t7 = tgts[rA+7];
        union { unsigned int u[4]; bf16x8 v; } A0, A1, B;
        A0.u[0] = ((t0==cA)?0x3F80u:0u) | (((t1==cA)?0x3F80u:0u) << 16);
        A0.u[1] = ((t2==cA)?0x3F80u:0u) | (((t3==cA)?0x3F80u:0u) << 16);
        A0.u[2] = ((t4==cA)?0x3F80u:0u) | (((t5==cA)?0x3F80u:0u) << 16);
        A0.u[3] = ((t6==cA)?0x3F80u:0u) | (((t7==cA)?0x3F80u:0u) << 16);
        A1.u[0] = ((t0==cB)?0x3F80u:0u) | (((t1==cB)?0x3F80u:0u) << 16);
        A1.u[1] = ((t2==cB)?0x3F80u:0u) | (((t3==cB)?0x3F80u:0u) << 16);
        A1.u[2] = ((t4==cB)?0x3F80u:0u) | (((t5==cB)?0x3F80u:0u) << 16);
        A1.u[3] = ((t6==cB)?0x3F80u:0u) | (((t7==cB)?0x3F80u:0u) << 16);
        const int kr = ks * 16 + g8;
        #pragma unroll
        for (int p = 0; p < 4; ++p) {
            const unsigned int lo = pb[(kr + 2*p    ) * 256 + col];
            const unsigned int hi = pb[(kr + 2*p + 1) * 256 + col];
            B.u[p] = lo | (hi << 16);
        }
        a0r = __builtin_amdgcn_mfma_f32_32x32x16_bf16(A0.v, B.v, a0r, 0, 0, 0);
        a1r = __builtin_amdgcn_mfma_f32_32x32x16_bf16(A1.v, B.v, a1r, 0, 0, 0);
    }
}

// ---- k_main: streaming MFMA scatter-add; classic 2-barrier; LDS-cached cent ----
__global__ __launch_bounds__(512, 4)
void k_main(const float* __restrict__ pred, const float* __restrict__ cent,
            const float* __restrict__ count, const int* __restrict__ tgt,
            float* __restrict__ ws)
{
    __shared__ unsigned short pbf[64 * 256];   // 32 KB bf16 chunk [r][d]
    __shared__ unsigned short cbf[NC * 256];   // 32 KB bf16 centroids [c][d]
    __shared__ int   tgt_s[512];
    __shared__ float inv_s[64];
    __shared__ float vec_s[512];
    __shared__ float sw_s[8][64];

    const int tid  = threadIdx.x;
    const int w    = tid >> 6;        // 8 waves; wave owns dims [32w, 32w+32)
    const int lane = tid & 63;
    const int base = blockIdx.x * 512;

    tgt_s[tid] = tgt[base + tid];
    if (tid < 64) inv_s[tid] = 1.0f / count[tid];
    {
        const float2* c2 = (const float2*)cent;
        unsigned int* cb32 = (unsigned int*)cbf;
        #pragma unroll
        for (int i = 0; i < 16; ++i) {
            const int o = i * 512 + tid;
            const float2 cf = c2[o];
            cb32[o] = bf16rne2(cf.x, cf.y);
        }
    }
    __syncthreads();

    const float4* pred4 = (const float4*)pred;
    const int d0 = w * 32;

    f32x16 acc0 = {};   // classes [0,32)  x dims [d0,d0+32)
    f32x16 acc1 = {};   // classes [32,64) x dims [d0,d0+32)

    #pragma unroll 1
    for (int ch = 0; ch < 8; ++ch) {
        // stage: load 8 rows (row = ch*64 + 8i + w), all loads issued together
        const size_t gr = (size_t)(base + ch * 64) * 64 + lane;
        float4 p0 = pred4[gr + (size_t)( 0 + w) * 64];
        float4 p1 = pred4[gr + (size_t)( 8 + w) * 64];
        float4 p2 = pred4[gr + (size_t)(16 + w) * 64];
        float4 p3 = pred4[gr + (size_t)(24 + w) * 64];
        float4 p4 = pred4[gr + (size_t)(32 + w) * 64];
        float4 p5 = pred4[gr + (size_t)(40 + w) * 64];
        float4 p6 = pred4[gr + (size_t)(48 + w) * 64];
        float4 p7 = pred4[gr + (size_t)(56 + w) * 64];

#define ROW(pp, i)                                                             \
        {                                                                      \
            const int rc = 8*(i) + w;                                          \
            const int r  = ch * 64 + rc;                                       \
            const int c  = tgt_s[r];                                           \
            const float iv = inv_s[c];                                         \
            const uint2 cu = *(const uint2*)&cbf[c * 256 + lane * 4];          \
            const float dx = bflo(cu.x) - pp.x * iv;                           \
            const float dy = bfhi(cu.x) - pp.y * iv;                           \
            const float dz = bflo(cu.y) - pp.z * iv;                           \
            const float dw = bfhi(cu.y) - pp.w * iv;                           \
            float ss = dx*dx + dy*dy + dz*dz + dw*dw;                          \
            ss = dpp_sum64(ss);                                                \
            if (lane == 63) vec_s[r] = sqrtf(ss);                              \
            *(uint2*)&pbf[rc * 256 + lane * 4] =                               \
                make_uint2(bf16rne2(pp.x, pp.y), bf16rne2(pp.z, pp.w));        \
        }
        ROW(p0, 0) ROW(p1, 1) ROW(p2, 2) ROW(p3, 3)
        ROW(p4, 4) ROW(p5, 5) ROW(p6, 6) ROW(p7, 7)
#undef ROW
        __syncthreads();
        do_mfma_chunk(pbf, tgt_s, ch * 64, lane, d0, acc0, acc1);
        __syncthreads();
    }

    // write bf16 partials (C/D layout: col=lane&31, row=(reg&3)+8*(reg>>2)+4*(lane>>5))
    unsigned short* pp = (unsigned short*)(ws + OFF_PART) + (size_t)blockIdx.x * CD;
    const int dim = d0 + (lane & 31);
    #pragma unroll
    for (int reg = 0; reg < 16; ++reg) {
        const int crow = (reg & 3) + 8 * (reg >> 2) + 4 * (lane >> 5);
        pp[(     crow) * 256 + dim] = bf16rne1(acc0[reg]);
        pp[(32 + crow) * 256 + dim] = bf16rne1(acc1[reg]);
    }

    // block-end per-class s reduction (no atomics)
    {
        const float vv = vec_s[w * 64 + lane];
        const int   cc = tgt_s[w * 64 + lane];
        float accs = 0.f;
        for (int k = 0; k < NC; ++k) {
            float sel = (cc == k) ? vv : 0.f;
            sel = dpp_sum64(sel);
            const float tot = __shfl(sel, 63, 64);
            accs += (lane == k) ? tot : 0.f;
        }
        sw_s[w][lane] = accs;
    }
    __syncthreads();
    if (w == 0) {
        float s = 0.f;
        #pragma unroll
        for (int q = 0; q < 8; ++q) s += sw_s[q][lane];
        ws[OFF_SPART + blockIdx.x * 64 + lane] = s;
    }
}

// ---- k_red (WIDE): 1024 blocks reduce bf16 partials -> 4 f32 stage2 slabs;
//      16 blocks reduce s_part -> 16 s_stage2 rows ----
__global__ __launch_bounds__(256)
void k_red(float* __restrict__ ws)
{
    const int b = blockIdx.x, t = threadIdx.x;
    __shared__ float red[4][64];
    if (b < 1024) {
        const int pg = b >> 8, eg = b & 255;
        const int e  = eg * 64 + (t & 63);
        const int ps = t >> 6;                     // 0..3
        const unsigned short* pp = (const unsigned short*)(ws + OFF_PART) + e;
        float s = 0.f;
        const int pstart = pg * 128 + ps * 32;
        #pragma unroll 8
        for (int p = pstart; p < pstart + 32; ++p) s += bfup(pp[(size_t)p * CD]);
        red[ps][t & 63] = s;
        __syncthreads();
        if (t < 64)
            ws[OFF_ST2 + pg * CD + eg * 64 + t]
                = red[0][t] + red[1][t] + red[2][t] + red[3][t];
    } else {
        const int q = b - 1024;                    // 0..15
        const int c = t & 63, pq = t >> 6;
        float s = 0.f;
        #pragma unroll
        for (int i = 0; i < 8; ++i)
            s += ws[OFF_SPART + (q * 32 + pq * 8 + i) * 64 + c];
        red[pq][c] = s;
        __syncthreads();
        if (t < 64)
            ws[OFF_SST2 + q * 64 + t]
                = red[0][t] + red[1][t] + red[2][t] + red[3][t];
    }
}

// ---- k2: cent_new = cent + acc*inv; abs partials; s_final ----
__global__ __launch_bounds__(256)
void k2_build(const float* __restrict__ cent, const float* __restrict__ count,
              const float* __restrict__ dist, float* __restrict__ ws)
{
    const int c = blockIdx.x, i = threadIdx.x;
    const float inv = 1.0f / count[c];
    const int o = c * 256 + i;
    float tsum = 0.f;
    #pragma unroll
    for (int pg = 0; pg < 4; ++pg) tsum += ws[OFF_ST2 + pg * CD + o];
    const float val = cent[o] + tsum * inv;
    ws[OFF_CENT + o] = val;
    float a = fabsf(val);
    #pragma unroll
    for (int off = 32; off > 0; off >>= 1) a += __shfl_xor(a, off, 64);
    __shared__ float ra[4];
    if ((i & 63) == 0) ra[i >> 6] = a;
    __syncthreads();
    if (i == 0) {
        float sv = 0.f;
        #pragma unroll
        for (int q = 0; q < 16; ++q) sv += ws[OFF_SST2 + q * 64 + c];
        ws[OFF_ABS + c] = ra[0] + ra[1] + ra[2] + ra[3];
        ws[OFF_SF  + c] = sqrtf(dist[c] + sv) / count[c];
    }
}

// ---- k3: pairwise terms ----
__global__ __launch_bounds__(256)
void k3_pairs(const float* __restrict__ cw, float* __restrict__ ws)
{
    const int i    = blockIdx.x;
    const int tid  = threadIdx.x;
    const int lane = tid & 63;
    const int w    = tid >> 6;
    const float4* c4 = (const float4*)(ws + OFF_CENT);
    const float*  sf = ws + OFF_SF;

    float4 ci = c4[i * 64 + lane];
    float  si = sf[i];
    float acc = 0.f;
    for (int j = w; j < NC; j += 4) {
        if (j == i) continue;
        float4 cj = c4[j * 64 + lane];
        float dx = ci.x - cj.x, dy = ci.y - cj.y;
        float dz = ci.z - cj.z, dw = ci.w - cj.w;
        float ss = dx*dx + dy*dy + dz*dz + dw*dw;
        #pragma unroll
        for (int o = 32; o > 0; o >>= 1) ss += __shfl_xor(ss, o, 64);
        acc += cw[i * NC + j] * (si + sf[j]) / sqrtf(ss);
    }
    __shared__ float wsum[4];
    if (lane == 0) wsum[w] = acc;
    __syncthreads();
    if (tid == 0) ws[OFF_PAIR + i] = wsum[0] + wsum[1] + wsum[2] + wsum[3];
}

// ---- k4: final scalar ----
__global__ __launch_bounds__(64)
void k4_final(const float* __restrict__ ws, float* __restrict__ out)
{
    const int t = threadIdx.x;
    float a = ws[OFF_ABS + t];
    float p = ws[OFF_PAIR + t];
    #pragma unroll
    for (int o = 32; o > 0; o >>= 1) {
        a += __shfl_xor(a, o, 64);
        p += __shfl_xor(p, o, 64);
    }
    if (t == 0) out[0] = p / 64.0f * 63.0f + a * 1e-6f;
}

extern "C" void kernel_launch(void* const* d_in, const int* in_sizes, int n_in,
                              void* d_out, int out_size, void* d_ws, size_t ws_size,
                              hipStream_t stream)
{
    const float* pred  = (const float*)d_in[0];
    const float* cent  = (const float*)d_in[1];
    const float* dist  = (const float*)d_in[2];
    const float* count = (const float*)d_in[3];
    const float* cw    = (const float*)d_in[4];
    const int*   tgt   = (const int*)d_in[5];
    float* ws  = (float*)d_ws;
    float* out = (float*)d_out;

    // no atomics anywhere -> no memset needed
    k_main  <<<NBLK, 512, 0, stream>>>(pred, cent, count, tgt, ws);
    k_red   <<<1040, 256, 0, stream>>>(ws);
    k2_build<<<NC,   256, 0, stream>>>(cent, count, dist, ws);
    k3_pairs<<<NC,   256, 0, stream>>>(cw, ws);
    k4_final<<<1,     64, 0, stream>>>(ws, out);
}